// Round 12
// baseline (105.935 us; speedup 1.0000x reference)
//
#include <hip/hip_runtime.h>

typedef float f32x4 __attribute__((ext_vector_type(4)));
typedef int   i32x4 __attribute__((ext_vector_type(4)));
typedef short bf16x8 __attribute__((ext_vector_type(8)));

#define MFMA16(a, b, c) __builtin_amdgcn_mfma_f32_16x16x32_bf16((a), (b), (c), 0, 0, 0)

#define NN 4096
#define DD 256
#define SCALE 0.0625f
#define THR 8.0f

static __device__ __forceinline__ unsigned short f2bf(float f) {
  unsigned int u = __float_as_uint(f);
  u += 0x7FFFu + ((u >> 16) & 1u);   // round-to-nearest-even
  return (unsigned short)(u >> 16);
}

static __device__ __forceinline__ unsigned pack2bf(float lo, float hi) {
  return (unsigned)f2bf(lo) | ((unsigned)f2bf(hi) << 16);
}

static __device__ __forceinline__ float bf2f(unsigned short u) {
  return __uint_as_float((unsigned)u << 16);
}

static __device__ __forceinline__ float softplusf(float x) {
  return (x > 20.f) ? x : log1pf(__expf(x));
}

// ---------------------------------------------------------------------------
// Prep: q/k transpose [B,C,N] -> [B,N,C] (+pos), cast bf16; q pre-scaled.
// ---------------------------------------------------------------------------
__global__ __launch_bounds__(256) void prep_qk(
    const float* __restrict__ q, const float* __restrict__ k,
    const float* __restrict__ qp, const float* __restrict__ kp,
    unsigned short* __restrict__ qbf, unsigned short* __restrict__ kbf) {
  int n0 = blockIdx.x * 32, c0 = blockIdx.y * 32;
  int b = blockIdx.z & 1, which = blockIdx.z >> 1;
  const float* src = which ? k : q;
  const float* pos = which ? kp : qp;
  unsigned short* dst = which ? kbf : qbf;
  float scl = which ? 1.0f : SCALE;

  __shared__ float tile[32][33];
  int tx = threadIdx.x & 31, ty = threadIdx.x >> 5;
#pragma unroll
  for (int i = 0; i < 4; ++i) {
    int c = c0 + ty + i * 8;
    tile[ty + i * 8][tx] = src[((size_t)(b * DD + c)) * NN + n0 + tx];
  }
  __syncthreads();
#pragma unroll
  for (int i = 0; i < 4; ++i) {
    int n = n0 + ty + i * 8;
    float v = (tile[tx][ty + i * 8] + pos[(size_t)n * DD + c0 + tx]) * scl;
    dst[((size_t)(b * NN + n)) * DD + c0 + tx] = f2bf(v);
  }
}

// ---------------------------------------------------------------------------
// Prep: v cast (keeps [B,C,N] layout == V^T) + column sum.
// ---------------------------------------------------------------------------
__global__ __launch_bounds__(256) void prep_v(
    const float* __restrict__ src, unsigned short* __restrict__ vbf,
    float* __restrict__ colsum) {
  int row = blockIdx.x;  // b*256 + c
  const float* s = src + (size_t)row * NN;
  unsigned short* d = vbf + (size_t)row * NN;
  int tid = threadIdx.x;
  float sum = 0.f;
#pragma unroll
  for (int i = 0; i < 16; ++i) {
    int n = tid + i * 256;
    float v = s[n];
    sum += v;
    d[n] = f2bf(v);
  }
#pragma unroll
  for (int off = 1; off < 64; off <<= 1) sum += __shfl_xor(sum, off);
  __shared__ float ps[4];
  if ((tid & 63) == 0) ps[tid >> 6] = sum;
  __syncthreads();
  if (tid == 0) colsum[row] = ps[0] + ps[1] + ps[2] + ps[3];
}

// ---------------------------------------------------------------------------
// Prep: mask_map scalars (sum of squares of nearest-resized mask).
// ---------------------------------------------------------------------------
__global__ __launch_bounds__(256) void prep_mask(
    const float* __restrict__ me, const float* __restrict__ mm,
    float* __restrict__ msums) {
  int b = blockIdx.x >> 1, which = blockIdx.x & 1;
  const float* m = which ? mm : me;
  int tid = threadIdx.x;
  float sum = 0.f;
#pragma unroll
  for (int i = 0; i < 16; ++i) {
    int p = tid + i * 256;
    int y = p >> 6, x = p & 63;
    float v = m[(size_t)(b * 128 + 2 * y) * 128 + 2 * x];
    sum += v * v;
  }
#pragma unroll
  for (int off = 1; off < 64; off <<= 1) sum += __shfl_xor(sum, off);
  __shared__ float ps[4];
  if ((tid & 63) == 0) ps[tid >> 6] = sum;
  __syncthreads();
  if (tid == 0) msums[blockIdx.x] = ps[0] + ps[1] + ps[2] + ps[3];
}

// ---------------------------------------------------------------------------
// Register-staged K/V tiles (proven r11 mappings, unchanged).
// K: global row kv stored at LDS row rho = bitswap(kv bits 2<->3), XOR swz.
// V: [256 d][32 kv], chunks ^= (d>>1)&3.
// ---------------------------------------------------------------------------
static __device__ __forceinline__ void load_k(
    const unsigned short* __restrict__ kb, int kvb, int wid, int lane, i32x4* kr) {
  int krow = wid * 8 + (lane >> 3);
  int kc = lane & 7;
  const unsigned short* kp = kb + (size_t)(kvb + krow) * DD;
#pragma unroll
  for (int i = 0; i < 4; ++i)
    kr[i] = *(const i32x4*)(kp + ((kc | (i << 3)) << 3));
}

static __device__ __forceinline__ void load_v(
    const unsigned short* __restrict__ vb, int kvb, int wid, int lane, i32x4* vr) {
  int vd = wid * 64 + lane;
  const unsigned short* vp = vb + (size_t)vd * NN + kvb;
#pragma unroll
  for (int i = 0; i < 4; ++i)
    vr[i] = *(const i32x4*)(vp + (i << 3));
}

static __device__ __forceinline__ void write_k(
    char* kdst, int wid, int lane, const i32x4* kr) {
  int krow = wid * 8 + (lane >> 3);
  int kc = lane & 7;
  int prow = ((krow & 4) << 2) | ((krow >> 3) << 2) | (krow & 3);  // kv->rho
  int rx = prow & 7;
#pragma unroll
  for (int i = 0; i < 4; ++i)
    *(i32x4*)(kdst + prow * 512 + (((kc | (i << 3)) ^ rx) << 4)) = kr[i];
}

static __device__ __forceinline__ void write_v(
    char* vdst, int wid, int lane, const i32x4* vr) {
  int vd = wid * 64 + lane;
  int vx = (vd >> 1) & 3;
#pragma unroll
  for (int i = 0; i < 4; ++i)
    *(i32x4*)(vdst + vd * 64 + ((i ^ vx) << 4)) = vr[i];
}

// ---------------------------------------------------------------------------
// Flash attention partial, QBLK=32/wave (two 16-q tiles h=0,1): every LDS
// K/V fragment read feeds 4 MFMAs (2x the FLOPs per LDS byte of round 11).
// Swapped-QK^T, in-register softmax, defer-max/defer-sum, shuffle-free P
// handoff via K-row permutation. K dbuf + V dbuf (64KB), ONE barrier/iter.
// 4 waves/block = 128 q/block; grid 64*ks (ks=8 -> 512 = 2 blocks/CU).
// ---------------------------------------------------------------------------
__global__ __launch_bounds__(256, 1) void attn_partial(
    const unsigned short* __restrict__ qbf,
    const unsigned short* __restrict__ kbf,
    const unsigned short* __restrict__ vbf,
    unsigned short* __restrict__ opartb, float* __restrict__ mlpart, int ks) {
  // XCD-chunked swizzle: consecutive bid chunk per XCD -> shared KV slice.
  int hwb = blockIdx.x;
  int bid = (hwb & 7) * ((int)gridDim.x >> 3) + (hwb >> 3);
  int qblk = bid & 31;           // 128-q block within (b,s)
  int combo = bid >> 5;          // (b, s)
  int b = combo / ks, sidx = combo % ks;
  int kvlen = NN / ks;
  int kv0 = sidx * kvlen;
  int nt = kvlen >> 5;

  int tid = threadIdx.x, wid = tid >> 6, lane = tid & 63;
  int ll = lane & 15, lg = lane >> 4;
  int qt32 = qblk * 4 + wid;     // this wave's 32-row q tile (0..127)

  __shared__ __align__(16) unsigned short Klds[2][32 * 256];
  __shared__ __align__(16) unsigned short Vlds[2][256 * 32];

  const unsigned short* kb = kbf + (size_t)b * NN * DD;
  const unsigned short* vb = vbf + (size_t)b * DD * NN;

  // Q B-fragments, two 16-q tiles: q = h*16+ll, k = kd*32+lg*8+j (SCALE folded)
  bf16x8 qB[2][8];
  {
    const unsigned short* qp0 = qbf + ((size_t)b * NN + (size_t)qt32 * 32) * DD;
#pragma unroll
    for (int h = 0; h < 2; ++h)
#pragma unroll
      for (int kd = 0; kd < 8; ++kd)
        qB[h][kd] = *(const bf16x8*)(qp0 + (size_t)(h * 16 + ll) * DD + kd * 32 + lg * 8);
  }

  f32x4 o[2][16];
#pragma unroll
  for (int h = 0; h < 2; ++h)
#pragma unroll
    for (int db = 0; db < 16; ++db) o[h][db] = (f32x4){0.f, 0.f, 0.f, 0.f};
  float m_ref[2] = {-1e30f, -1e30f};
  float sum_lane[2] = {0.f, 0.f};

  i32x4 kr[4], vr[4];
  // ---- prologue: stage tile 0, publish
  load_k(kb, kv0, wid, lane, kr);
  load_v(vb, kv0, wid, lane, vr);
  write_k((char*)&Klds[0][0], wid, lane, kr);
  write_v((char*)&Vlds[0][0], wid, lane, vr);
  __syncthreads();

  int buf = 0;
  for (int tt = 0; tt < nt; ++tt) {
    bool more = (tt + 1 < nt);
    // K(t+1) loads issued before QK (latency hides under QK+softmax)
    if (more) load_k(kb, kv0 + (tt + 1) * 32, wid, lane, kr);

    const unsigned short* Kc = &Klds[buf][0];

    // ---- S^T = K Q^T, both h tiles share every kf read
    f32x4 st[2][2];
    st[0][0] = (f32x4){0.f, 0.f, 0.f, 0.f};
    st[0][1] = (f32x4){0.f, 0.f, 0.f, 0.f};
    st[1][0] = (f32x4){0.f, 0.f, 0.f, 0.f};
    st[1][1] = (f32x4){0.f, 0.f, 0.f, 0.f};
    __builtin_amdgcn_s_setprio(1);
#pragma unroll
    for (int t = 0; t < 2; ++t) {
      int row = t * 16 + ll;
      int rx = row & 7;
      const unsigned short* krd = Kc + row * 256;
#pragma unroll
      for (int kd = 0; kd < 8; ++kd) {
        bf16x8 kf = *(const bf16x8*)(krd + ((((kd << 2) | lg) ^ rx) << 3));
        st[0][t] = MFMA16(kf, qB[0][kd], st[0][t]);
        st[1][t] = MFMA16(kf, qB[1][kd], st[1][t]);
      }
    }
    __builtin_amdgcn_s_setprio(0);

    // K(t+1) publish; V(t+1) loads issued (hide under softmax+PV)
    if (more) {
      write_k((char*)&Klds[buf ^ 1][0], wid, lane, kr);
      load_v(vb, kv0 + (tt + 1) * 32, wid, lane, vr);
    }

    // ---- defer-max check (per h), slow path rare
    float tm0 = fmaxf(fmaxf(fmaxf(st[0][0][0], st[0][0][1]), fmaxf(st[0][0][2], st[0][0][3])),
                      fmaxf(fmaxf(st[0][1][0], st[0][1][1]), fmaxf(st[0][1][2], st[0][1][3])));
    float tm1 = fmaxf(fmaxf(fmaxf(st[1][0][0], st[1][0][1]), fmaxf(st[1][0][2], st[1][0][3])),
                      fmaxf(fmaxf(st[1][1][0], st[1][1][1]), fmaxf(st[1][1][2], st[1][1][3])));
    if (__any((tm0 > m_ref[0] + THR) || (tm1 > m_ref[1] + THR))) {
      float tq0 = fmaxf(tm0, __shfl_xor(tm0, 16));
      tq0 = fmaxf(tq0, __shfl_xor(tq0, 32));
      float tq1 = fmaxf(tm1, __shfl_xor(tm1, 16));
      tq1 = fmaxf(tq1, __shfl_xor(tq1, 32));
      float mn0 = fmaxf(m_ref[0], tq0), mn1 = fmaxf(m_ref[1], tq1);
      float sc0 = __expf(m_ref[0] - mn0), sc1 = __expf(m_ref[1] - mn1);
      sum_lane[0] *= sc0; sum_lane[1] *= sc1;
      m_ref[0] = mn0; m_ref[1] = mn1;
#pragma unroll
      for (int r = 0; r < 4; ++r) {
        float sv0 = __shfl(sc0, (lg << 2) + r);
        float sv1 = __shfl(sc1, (lg << 2) + r);
#pragma unroll
        for (int db = 0; db < 16; ++db) { o[0][db][r] *= sv0; o[1][db][r] *= sv1; }
      }
    }

    // ---- P = exp(S - m_ref); register order IS the PV A-fragment (per h)
    bf16x8 pa[2];
#pragma unroll
    for (int h = 0; h < 2; ++h) {
      unsigned p0, p1, p2, p3;
      float a0 = __expf(st[h][0][0] - m_ref[h]);
      float a1 = __expf(st[h][0][1] - m_ref[h]);
      float a2 = __expf(st[h][0][2] - m_ref[h]);
      float a3 = __expf(st[h][0][3] - m_ref[h]);
      float b0 = __expf(st[h][1][0] - m_ref[h]);
      float b1 = __expf(st[h][1][1] - m_ref[h]);
      float b2 = __expf(st[h][1][2] - m_ref[h]);
      float b3 = __expf(st[h][1][3] - m_ref[h]);
      sum_lane[h] += ((a0 + a1) + (a2 + a3)) + ((b0 + b1) + (b2 + b3));
      p0 = pack2bf(a0, a1); p1 = pack2bf(a2, a3);
      p2 = pack2bf(b0, b1); p3 = pack2bf(b2, b3);
      i32x4 fi = (i32x4){(int)p0, (int)p1, (int)p2, (int)p3};
      pa[h] = __builtin_bit_cast(bf16x8, fi);
    }

    // ---- O += P V, both h tiles share every vf read
    const unsigned short* Vc = &Vlds[buf][0];
    __builtin_amdgcn_s_setprio(1);
#pragma unroll
    for (int db = 0; db < 16; ++db) {
      int d = (db << 4) + ll;
      bf16x8 vf = *(const bf16x8*)(Vc + d * 32 + ((lg ^ ((d >> 1) & 3)) << 3));
      o[0][db] = MFMA16(pa[0], vf, o[0][db]);
      o[1][db] = MFMA16(pa[1], vf, o[1][db]);
    }
    __builtin_amdgcn_s_setprio(0);

    // ---- V(t+1) publish, single barrier
    if (more) write_v((char*)&Vlds[buf ^ 1][0], wid, lane, vr);
    __syncthreads();
    buf ^= 1;
  }

  // ---- final row-sum reduce (once per kernel)
#pragma unroll
  for (int h = 0; h < 2; ++h) {
    sum_lane[h] += __shfl_xor(sum_lane[h], 16);
    sum_lane[h] += __shfl_xor(sum_lane[h], 32);
  }

  // ---- epilogue: two 16-q slots (combine kernel unchanged)
#pragma unroll
  for (int h = 0; h < 2; ++h) {
    size_t slot = (size_t)(b * 256 + qt32 * 2 + h) * ks + sidx;
    unsigned short* op = opartb + slot * 4096;
#pragma unroll
    for (int db = 0; db < 16; ++db) {
      unsigned u0 = pack2bf(o[h][db][0], o[h][db][1]);
      unsigned u1 = pack2bf(o[h][db][2], o[h][db][3]);
      unsigned* p = (unsigned*)&op[(size_t)((db * 16 + ll) * 16 + lg * 4)];
      p[0] = u0;
      p[1] = u1;
    }
    if (lg == 0) {
      float* mlp = mlpart + slot * 32;
      mlp[ll * 2 + 0] = m_ref[h];
      mlp[ll * 2 + 1] = sum_lane[h];
    }
  }
}

// ---------------------------------------------------------------------------
// Combine: merge ks bf16 partials, normalize, add softplus-bias * colsum.
// grid 512 = (b, qt16); thread = d.
// ---------------------------------------------------------------------------
__global__ __launch_bounds__(256) void attn_combine(
    const unsigned short* __restrict__ opartb, const float* __restrict__ mlpart,
    const float* __restrict__ colsum, const float* __restrict__ msums,
    const float* __restrict__ bias_eye, const float* __restrict__ bias_mouth,
    float* __restrict__ out, int ks) {
  int gb = blockIdx.x;
  int b = gb >> 8, qt16 = gb & 255;
  int tid = threadIdx.x;
  __shared__ float wtab[8][16];
  size_t slot0 = (size_t)(b * 256 + qt16) * ks;

  if (tid < 16) {
    int q = tid;
    float m[8], l[8], w[8];
    float M = -1e30f;
#pragma unroll
    for (int s = 0; s < 8; ++s) {
      if (s < ks) {
        m[s] = mlpart[(slot0 + s) * 32 + q * 2 + 0];
        l[s] = mlpart[(slot0 + s) * 32 + q * 2 + 1];
        M = fmaxf(M, m[s]);
      } else { m[s] = -1e30f; l[s] = 0.f; }
    }
    float L = 0.f;
#pragma unroll
    for (int s = 0; s < 8; ++s) {
      w[s] = (s < ks) ? __expf(m[s] - M) : 0.f;
      L += l[s] * w[s];
    }
    float invL = 1.f / L;
#pragma unroll
    for (int s = 0; s < 8; ++s) wtab[s][q] = w[s] * invL;
  }
  __syncthreads();

  int d = tid;
  float sb = softplusf(bias_eye[0] * msums[b * 2 + 0]) +
             softplusf(bias_mouth[0] * msums[b * 2 + 1]);
  float cs = colsum[b * DD + d] * sb;

  float acc[16];
#pragma unroll
  for (int q = 0; q < 16; ++q) acc[q] = cs;

#pragma unroll
  for (int s = 0; s < 8; ++s) {
    if (s < ks) {
      const unsigned short* op = opartb + (slot0 + s) * 4096 + d * 16;
#pragma unroll
      for (int q = 0; q < 16; ++q)
        acc[q] += wtab[s][q] * bf2f(op[q]);
    }
  }

  float* ob = out + ((size_t)(b * DD + d)) * NN + qt16 * 16;
#pragma unroll
  for (int g = 0; g < 4; ++g) {
    f32x4 v = (f32x4){acc[g * 4 + 0], acc[g * 4 + 1], acc[g * 4 + 2], acc[g * 4 + 3]};
    *(f32x4*)&ob[g * 4] = v;
  }
}

// ---------------------------------------------------------------------------
extern "C" void kernel_launch(void* const* d_in, const int* in_sizes, int n_in,
                              void* d_out, int out_size, void* d_ws, size_t ws_size,
                              hipStream_t stream) {
  (void)in_sizes; (void)n_in; (void)out_size;
  const float* queries    = (const float*)d_in[0];
  const float* keys       = (const float*)d_in[1];
  const float* values     = (const float*)d_in[2];
  const float* mask_eye   = (const float*)d_in[3];
  const float* mask_mouth = (const float*)d_in[4];
  const float* q_pos      = (const float*)d_in[5];
  const float* k_pos      = (const float*)d_in[6];
  const float* bias_eye   = (const float*)d_in[7];
  const float* bias_mouth = (const float*)d_in[8];
  float* out = (float*)d_out;

  char* w = (char*)d_ws;
  unsigned short* qbf = (unsigned short*)(w);                     // 4 MB
  unsigned short* kbf = (unsigned short*)(w + ((size_t)4 << 20)); // 4 MB
  unsigned short* vbf = (unsigned short*)(w + ((size_t)8 << 20)); // 4 MB
  float* colsum = (float*)(w + ((size_t)12 << 20));               // 1 KB
  float* msums  = (float*)(w + ((size_t)12 << 20) + 4096);        // 16 B

  const size_t opart_off = ((size_t)12 << 20) + 8192;
  const size_t opart_chunk = (size_t)512 * 8192;  // per split: 512 slots*8KB bf16
  const size_t ml_chunk = (size_t)512 * 128;      // per split: 512 slots*128B

  int ks = 1;
  for (int cand = 8; cand >= 1; cand >>= 1) {
    if (ws_size >= opart_off + (size_t)cand * (opart_chunk + ml_chunk)) { ks = cand; break; }
  }

  unsigned short* opartp = (unsigned short*)(w + opart_off);
  float* mlp = (float*)(w + opart_off + (size_t)ks * opart_chunk);

  prep_qk<<<dim3(128, 8, 4), 256, 0, stream>>>(queries, keys, q_pos, k_pos, qbf, kbf);
  prep_v<<<512, 256, 0, stream>>>(values, vbf, colsum);
  prep_mask<<<4, 256, 0, stream>>>(mask_eye, mask_mouth, msums);

  attn_partial<<<64 * ks, 256, 0, stream>>>(qbf, kbf, vbf, opartp, mlp, ks);
  attn_combine<<<512, 256, 0, stream>>>(opartp, mlp, colsum, msums,
                                        bias_eye, bias_mouth, out, ks);
}

// Round 13
// 81.156 us; speedup vs baseline: 1.3053x; 1.3053x over previous
//
#include <hip/hip_runtime.h>

typedef float f32x4 __attribute__((ext_vector_type(4)));
typedef int   i32x4 __attribute__((ext_vector_type(4)));
typedef short bf16x8 __attribute__((ext_vector_type(8)));

#define MFMA16(a, b, c) __builtin_amdgcn_mfma_f32_16x16x32_bf16((a), (b), (c), 0, 0, 0)

#define NN 4096
#define DD 256
#define SCALE 0.0625f
#define THR 8.0f

static __device__ __forceinline__ unsigned short f2bf(float f) {
  unsigned int u = __float_as_uint(f);
  u += 0x7FFFu + ((u >> 16) & 1u);   // round-to-nearest-even
  return (unsigned short)(u >> 16);
}

static __device__ __forceinline__ unsigned pack2bf(float lo, float hi) {
  return (unsigned)f2bf(lo) | ((unsigned)f2bf(hi) << 16);
}

static __device__ __forceinline__ float bf2f(unsigned short u) {
  return __uint_as_float((unsigned)u << 16);
}

static __device__ __forceinline__ float softplusf(float x) {
  return (x > 20.f) ? x : log1pf(__expf(x));
}

// ---------------------------------------------------------------------------
// Prep: q/k transpose [B,C,N] -> [B,N,C] (+pos), cast bf16; q pre-scaled.
// ---------------------------------------------------------------------------
__global__ __launch_bounds__(256) void prep_qk(
    const float* __restrict__ q, const float* __restrict__ k,
    const float* __restrict__ qp, const float* __restrict__ kp,
    unsigned short* __restrict__ qbf, unsigned short* __restrict__ kbf) {
  int n0 = blockIdx.x * 32, c0 = blockIdx.y * 32;
  int b = blockIdx.z & 1, which = blockIdx.z >> 1;
  const float* src = which ? k : q;
  const float* pos = which ? kp : qp;
  unsigned short* dst = which ? kbf : qbf;
  float scl = which ? 1.0f : SCALE;

  __shared__ float tile[32][33];
  int tx = threadIdx.x & 31, ty = threadIdx.x >> 5;
#pragma unroll
  for (int i = 0; i < 4; ++i) {
    int c = c0 + ty + i * 8;
    tile[ty + i * 8][tx] = src[((size_t)(b * DD + c)) * NN + n0 + tx];
  }
  __syncthreads();
#pragma unroll
  for (int i = 0; i < 4; ++i) {
    int n = n0 + ty + i * 8;
    float v = (tile[tx][ty + i * 8] + pos[(size_t)n * DD + c0 + tx]) * scl;
    dst[((size_t)(b * NN + n)) * DD + c0 + tx] = f2bf(v);
  }
}

// ---------------------------------------------------------------------------
// Prep: v cast (keeps [B,C,N] layout == V^T) + column sum.
// ---------------------------------------------------------------------------
__global__ __launch_bounds__(256) void prep_v(
    const float* __restrict__ src, unsigned short* __restrict__ vbf,
    float* __restrict__ colsum) {
  int row = blockIdx.x;  // b*256 + c
  const float* s = src + (size_t)row * NN;
  unsigned short* d = vbf + (size_t)row * NN;
  int tid = threadIdx.x;
  float sum = 0.f;
#pragma unroll
  for (int i = 0; i < 16; ++i) {
    int n = tid + i * 256;
    float v = s[n];
    sum += v;
    d[n] = f2bf(v);
  }
#pragma unroll
  for (int off = 1; off < 64; off <<= 1) sum += __shfl_xor(sum, off);
  __shared__ float ps[4];
  if ((tid & 63) == 0) ps[tid >> 6] = sum;
  __syncthreads();
  if (tid == 0) colsum[row] = ps[0] + ps[1] + ps[2] + ps[3];
}

// ---------------------------------------------------------------------------
// Prep: mask_map scalars (sum of squares of nearest-resized mask).
// ---------------------------------------------------------------------------
__global__ __launch_bounds__(256) void prep_mask(
    const float* __restrict__ me, const float* __restrict__ mm,
    float* __restrict__ msums) {
  int b = blockIdx.x >> 1, which = blockIdx.x & 1;
  const float* m = which ? mm : me;
  int tid = threadIdx.x;
  float sum = 0.f;
#pragma unroll
  for (int i = 0; i < 16; ++i) {
    int p = tid + i * 256;
    int y = p >> 6, x = p & 63;
    float v = m[(size_t)(b * 128 + 2 * y) * 128 + 2 * x];
    sum += v * v;
  }
#pragma unroll
  for (int off = 1; off < 64; off <<= 1) sum += __shfl_xor(sum, off);
  __shared__ float ps[4];
  if ((tid & 63) == 0) ps[tid >> 6] = sum;
  __syncthreads();
  if (tid == 0) msums[blockIdx.x] = ps[0] + ps[1] + ps[2] + ps[3];
}

// ---------------------------------------------------------------------------
// Register-staged K/V tiles (proven r11 mappings, unchanged).
// K: global row kv stored at LDS row rho = bitswap(kv bits 2<->3), XOR swz
//    -> QK^T output registers land exactly in PV A-fragment order.
// V: [256 d][32 kv], chunks ^= (d>>1)&3.
// ---------------------------------------------------------------------------
static __device__ __forceinline__ void load_k(
    const unsigned short* __restrict__ kb, int kvb, int wid, int lane, i32x4* kr) {
  int krow = wid * 8 + (lane >> 3);
  int kc = lane & 7;
  const unsigned short* kp = kb + (size_t)(kvb + krow) * DD;
#pragma unroll
  for (int i = 0; i < 4; ++i)
    kr[i] = *(const i32x4*)(kp + ((kc | (i << 3)) << 3));
}

static __device__ __forceinline__ void load_v(
    const unsigned short* __restrict__ vb, int kvb, int wid, int lane, i32x4* vr) {
  int vd = wid * 64 + lane;
  const unsigned short* vp = vb + (size_t)vd * NN + kvb;
#pragma unroll
  for (int i = 0; i < 4; ++i)
    vr[i] = *(const i32x4*)(vp + (i << 3));
}

static __device__ __forceinline__ void write_k(
    char* kdst, int wid, int lane, const i32x4* kr) {
  int krow = wid * 8 + (lane >> 3);
  int kc = lane & 7;
  int prow = ((krow & 4) << 2) | ((krow >> 3) << 2) | (krow & 3);  // kv->rho
  int rx = prow & 7;
#pragma unroll
  for (int i = 0; i < 4; ++i)
    *(i32x4*)(kdst + prow * 512 + (((kc | (i << 3)) ^ rx) << 4)) = kr[i];
}

static __device__ __forceinline__ void write_v(
    char* vdst, int wid, int lane, const i32x4* vr) {
  int vd = wid * 64 + lane;
  int vx = (vd >> 1) & 3;
#pragma unroll
  for (int i = 0; i < 4; ++i)
    *(i32x4*)(vdst + vd * 64 + ((i ^ vx) << 4)) = vr[i];
}

// QK^T MFMA cluster over the permuted K tile. Lane (ll,lg) output:
// st[t][r] = S[kv = lg*8 + 4t + r][q = ll]   (via the rho bit-swap)
static __device__ __forceinline__ void compute_qk(
    const unsigned short* __restrict__ Kc, const bf16x8* qB, int ll, int lg,
    f32x4* st) {
  st[0] = (f32x4){0.f, 0.f, 0.f, 0.f};
  st[1] = (f32x4){0.f, 0.f, 0.f, 0.f};
  __builtin_amdgcn_s_setprio(1);
#pragma unroll
  for (int t = 0; t < 2; ++t) {
    int row = t * 16 + ll;
    int rx = row & 7;
    const unsigned short* krd = Kc + row * 256;
#pragma unroll
    for (int kd = 0; kd < 8; ++kd) {
      bf16x8 kf = *(const bf16x8*)(krd + ((((kd << 2) | lg) ^ rx) << 3));
      st[t] = MFMA16(kf, qB[kd], st[t]);
    }
  }
  __builtin_amdgcn_s_setprio(0);
}

// ---------------------------------------------------------------------------
// Flash attention partial (round-11 structure, best known): swapped-QK^T,
// in-register softmax with defer-max/defer-sum, pipelined QK(t+1)||softmax(t),
// shuffle-free P->PV handoff via K-row permutation. K dbuf + V tribuf (80KB),
// ONE barrier/iter. QBLK=16/wave, 4 waves/block, KVBLK=32.
// ks=4: grid 512 = exactly 2 blocks/CU (the LDS cap) in one round; larger ks
// only adds partial-O traffic without adding residency.
// ---------------------------------------------------------------------------
__global__ __launch_bounds__(256, 2) void attn_partial(
    const unsigned short* __restrict__ qbf,
    const unsigned short* __restrict__ kbf,
    const unsigned short* __restrict__ vbf,
    unsigned short* __restrict__ opartb, float* __restrict__ mlpart, int ks) {
  // XCD-chunked swizzle: consecutive bid chunk per XCD -> shared KV slice.
  int hwb = blockIdx.x;
  int bid = (hwb & 7) * ((int)gridDim.x >> 3) + (hwb >> 3);
  int qblk = bid & 63;           // 64-q block within (b,s)
  int combo = bid >> 6;          // (b, s)
  int b = combo / ks, sidx = combo % ks;
  int kvlen = NN / ks;
  int kv0 = sidx * kvlen;
  int nt = kvlen >> 5;

  int tid = threadIdx.x, wid = tid >> 6, lane = tid & 63;
  int ll = lane & 15, lg = lane >> 4;
  int qt16 = qblk * 4 + wid;     // this wave's 16-row q tile (0..255)

  __shared__ __align__(16) unsigned short Klds[2][32 * 256];
  __shared__ __align__(16) unsigned short Vlds[3][256 * 32];

  const unsigned short* kb = kbf + (size_t)b * NN * DD;
  const unsigned short* vb = vbf + (size_t)b * DD * NN;

  // Q B-fragments: col=ll -> q = ll, k = kd*32 + lg*8 + j  (SCALE folded)
  bf16x8 qB[8];
  {
    const unsigned short* qp0 = qbf + ((size_t)b * NN + (size_t)qt16 * 16) * DD;
#pragma unroll
    for (int kd = 0; kd < 8; ++kd)
      qB[kd] = *(const bf16x8*)(qp0 + (size_t)ll * DD + kd * 32 + lg * 8);
  }

  f32x4 o[16];
#pragma unroll
  for (int db = 0; db < 16; ++db) o[db] = (f32x4){0.f, 0.f, 0.f, 0.f};
  float m_ref = -1e30f;
  float sum_lane = 0.f;

  i32x4 kr[4], vr[4];
  // ---- prologue: stage tiles 0 and 1; QK(0); barrier protects K[0] reuse
  load_k(kb, kv0, wid, lane, kr);
  load_v(vb, kv0, wid, lane, vr);
  write_k((char*)&Klds[0][0], wid, lane, kr);
  write_v((char*)&Vlds[0][0], wid, lane, vr);
  if (nt > 1) {
    load_k(kb, kv0 + 32, wid, lane, kr);
    load_v(vb, kv0 + 32, wid, lane, vr);
    write_k((char*)&Klds[1][0], wid, lane, kr);
    write_v((char*)&Vlds[1][0], wid, lane, vr);
  }
  __syncthreads();

  f32x4 st[2];
  compute_qk(&Klds[0][0], qB, ll, lg, st);
  __syncthreads();   // all waves done reading K[0] before iter-0 overwrites it

  int vp = 0;        // V read slot (tt%3)
  int wp = 2;        // V write slot ((tt+2)%3)

  for (int tt = 0; tt < nt; ++tt) {
    bool have1 = (tt + 1 < nt);
    bool have2 = (tt + 2 < nt);
    if (have2) {
      load_k(kb, kv0 + (tt + 2) * 32, wid, lane, kr);
      load_v(vb, kv0 + (tt + 2) * 32, wid, lane, vr);
    }

    // ---- defer-max check on st (short; precedes exp)
    float tm = fmaxf(fmaxf(fmaxf(st[0][0], st[0][1]), fmaxf(st[0][2], st[0][3])),
                     fmaxf(fmaxf(st[1][0], st[1][1]), fmaxf(st[1][2], st[1][3])));
    if (__any(tm > m_ref + THR)) {
      float tq = fmaxf(tm, __shfl_xor(tm, 16));
      tq = fmaxf(tq, __shfl_xor(tq, 32));
      float mn = fmaxf(m_ref, tq);
      float sc = __expf(m_ref - mn);
      sum_lane *= sc;
      m_ref = mn;
#pragma unroll
      for (int r = 0; r < 4; ++r) {
        float sv = __shfl(sc, (lg << 2) + r);
#pragma unroll
        for (int db = 0; db < 16; ++db) o[db][r] *= sv;
      }
    }

    // ---- QK(t+1): MFMA pipe works while VALU does softmax(t) below
    f32x4 stn[2];
    if (have1) compute_qk(&Klds[(tt + 1) & 1][0], qB, ll, lg, stn);

    // ---- P = exp(S - m_ref), bf16-packed; per-lane partial sums only.
    // K-row permutation makes pk the PV A-fragment directly: kv = lg*8+{0..7}
    unsigned pk[2][2];
#pragma unroll
    for (int t = 0; t < 2; ++t) {
      float a0 = __expf(st[t][0] - m_ref);
      float a1 = __expf(st[t][1] - m_ref);
      float a2 = __expf(st[t][2] - m_ref);
      float a3 = __expf(st[t][3] - m_ref);
      sum_lane += (a0 + a1) + (a2 + a3);
      pk[t][0] = pack2bf(a0, a1);
      pk[t][1] = pack2bf(a2, a3);
    }
    i32x4 fi = (i32x4){(int)pk[0][0], (int)pk[0][1], (int)pk[1][0], (int)pk[1][1]};
    bf16x8 pa = __builtin_bit_cast(bf16x8, fi);

    // ---- O += P V  (B-frag: col=ll -> d = db*16+ll, k = kv) from V[vp]
    const unsigned short* Vc = &Vlds[vp][0];
    __builtin_amdgcn_s_setprio(1);
#pragma unroll
    for (int db = 0; db < 16; ++db) {
      int d = (db << 4) + ll;
      bf16x8 vf = *(const bf16x8*)(Vc + d * 32 + ((lg ^ ((d >> 1) & 3)) << 3));
      o[db] = MFMA16(pa, vf, o[db]);
    }
    __builtin_amdgcn_s_setprio(0);

    // ---- stage t+2: K into K[tt&1] (free), V into V[wp] (free)
    if (have2) {
      write_k((char*)&Klds[tt & 1][0], wid, lane, kr);
      write_v((char*)&Vlds[wp][0], wid, lane, vr);
    }
    __syncthreads();

    if (have1) { st[0] = stn[0]; st[1] = stn[1]; }
    vp = (vp == 2) ? 0 : vp + 1;
    wp = (wp == 2) ? 0 : wp + 1;
  }

  // ---- final row-sum reduce (once per kernel)
  sum_lane += __shfl_xor(sum_lane, 16);
  sum_lane += __shfl_xor(sum_lane, 32);

  // ---- epilogue: bf16 unnormalized O (layout [d][q] per slot) + (m,l)
  size_t slot = (size_t)(b * 256 + qt16) * ks + sidx;
  unsigned short* op = opartb + slot * 4096;
#pragma unroll
  for (int db = 0; db < 16; ++db) {
    unsigned u0 = pack2bf(o[db][0], o[db][1]);
    unsigned u1 = pack2bf(o[db][2], o[db][3]);
    unsigned* p = (unsigned*)&op[(size_t)((db * 16 + ll) * 16 + lg * 4)];
    p[0] = u0;
    p[1] = u1;
  }
  if (lg == 0) {
    float* mlp = mlpart + slot * 32;
    mlp[ll * 2 + 0] = m_ref;
    mlp[ll * 2 + 1] = sum_lane;
  }
}

// ---------------------------------------------------------------------------
// Combine: merge ks bf16 partials, normalize, add softplus-bias * colsum.
// grid 512 = (b, qt16); thread = d.
// ---------------------------------------------------------------------------
__global__ __launch_bounds__(256) void attn_combine(
    const unsigned short* __restrict__ opartb, const float* __restrict__ mlpart,
    const float* __restrict__ colsum, const float* __restrict__ msums,
    const float* __restrict__ bias_eye, const float* __restrict__ bias_mouth,
    float* __restrict__ out, int ks) {
  int gb = blockIdx.x;
  int b = gb >> 8, qt16 = gb & 255;
  int tid = threadIdx.x;
  __shared__ float wtab[8][16];
  size_t slot0 = (size_t)(b * 256 + qt16) * ks;

  if (tid < 16) {
    int q = tid;
    float m[8], l[8], w[8];
    float M = -1e30f;
#pragma unroll
    for (int s = 0; s < 8; ++s) {
      if (s < ks) {
        m[s] = mlpart[(slot0 + s) * 32 + q * 2 + 0];
        l[s] = mlpart[(slot0 + s) * 32 + q * 2 + 1];
        M = fmaxf(M, m[s]);
      } else { m[s] = -1e30f; l[s] = 0.f; }
    }
    float L = 0.f;
#pragma unroll
    for (int s = 0; s < 8; ++s) {
      w[s] = (s < ks) ? __expf(m[s] - M) : 0.f;
      L += l[s] * w[s];
    }
    float invL = 1.f / L;
#pragma unroll
    for (int s = 0; s < 8; ++s) wtab[s][q] = w[s] * invL;
  }
  __syncthreads();

  int d = tid;
  float sb = softplusf(bias_eye[0] * msums[b * 2 + 0]) +
             softplusf(bias_mouth[0] * msums[b * 2 + 1]);
  float cs = colsum[b * DD + d] * sb;

  float acc[16];
#pragma unroll
  for (int q = 0; q < 16; ++q) acc[q] = cs;

#pragma unroll
  for (int s = 0; s < 8; ++s) {
    if (s < ks) {
      const unsigned short* op = opartb + (slot0 + s) * 4096 + d * 16;
#pragma unroll
      for (int q = 0; q < 16; ++q)
        acc[q] += wtab[s][q] * bf2f(op[q]);
    }
  }

  float* ob = out + ((size_t)(b * DD + d)) * NN + qt16 * 16;
#pragma unroll
  for (int g = 0; g < 4; ++g) {
    f32x4 v = (f32x4){acc[g * 4 + 0], acc[g * 4 + 1], acc[g * 4 + 2], acc[g * 4 + 3]};
    *(f32x4*)&ob[g * 4] = v;
  }
}

// ---------------------------------------------------------------------------
extern "C" void kernel_launch(void* const* d_in, const int* in_sizes, int n_in,
                              void* d_out, int out_size, void* d_ws, size_t ws_size,
                              hipStream_t stream) {
  (void)in_sizes; (void)n_in; (void)out_size;
  const float* queries    = (const float*)d_in[0];
  const float* keys       = (const float*)d_in[1];
  const float* values     = (const float*)d_in[2];
  const float* mask_eye   = (const float*)d_in[3];
  const float* mask_mouth = (const float*)d_in[4];
  const float* q_pos      = (const float*)d_in[5];
  const float* k_pos      = (const float*)d_in[6];
  const float* bias_eye   = (const float*)d_in[7];
  const float* bias_mouth = (const float*)d_in[8];
  float* out = (float*)d_out;

  char* w = (char*)d_ws;
  unsigned short* qbf = (unsigned short*)(w);                     // 4 MB
  unsigned short* kbf = (unsigned short*)(w + ((size_t)4 << 20)); // 4 MB
  unsigned short* vbf = (unsigned short*)(w + ((size_t)8 << 20)); // 4 MB
  float* colsum = (float*)(w + ((size_t)12 << 20));               // 1 KB
  float* msums  = (float*)(w + ((size_t)12 << 20) + 4096);        // 16 B

  const size_t opart_off = ((size_t)12 << 20) + 8192;
  const size_t opart_chunk = (size_t)512 * 8192;  // per split: 512 slots*8KB bf16
  const size_t ml_chunk = (size_t)512 * 128;      // per split: 512 slots*128B

  // ks=4 preferred: grid 512 = exactly 2 blocks/CU (the LDS-capped residency);
  // larger ks adds only partial-O traffic.
  int ks = 1;
  for (int cand = 4; cand >= 1; cand >>= 1) {
    if (ws_size >= opart_off + (size_t)cand * (opart_chunk + ml_chunk)) { ks = cand; break; }
  }

  unsigned short* opartp = (unsigned short*)(w + opart_off);
  float* mlp = (float*)(w + opart_off + (size_t)ks * opart_chunk);

  prep_qk<<<dim3(128, 8, 4), 256, 0, stream>>>(queries, keys, q_pos, k_pos, qbf, kbf);
  prep_v<<<512, 256, 0, stream>>>(values, vbf, colsum);
  prep_mask<<<4, 256, 0, stream>>>(mask_eye, mask_mouth, msums);

  attn_partial<<<128 * ks, 256, 0, stream>>>(qbf, kbf, vbf, opartp, mlp, ks);
  attn_combine<<<512, 256, 0, stream>>>(opartp, mlp, colsum, msums,
                                        bias_eye, bias_mouth, out, ks);
}

// Round 14
// 77.402 us; speedup vs baseline: 1.3686x; 1.0485x over previous
//
#include <hip/hip_runtime.h>

typedef float f32x4 __attribute__((ext_vector_type(4)));
typedef int   i32x4 __attribute__((ext_vector_type(4)));
typedef short bf16x8 __attribute__((ext_vector_type(8)));

#define MFMA16(a, b, c) __builtin_amdgcn_mfma_f32_16x16x32_bf16((a), (b), (c), 0, 0, 0)

#define NN 4096
#define DD 256
#define SCALE 0.0625f
#define LOG2E 1.44269504089f
// softmax runs in log2 domain (log2e folded into Q prescale); THR = 8*log2e
#define THR2 11.5415603f

#define EXP2(x) __builtin_amdgcn_exp2f(x)

static __device__ __forceinline__ unsigned short f2bf(float f) {
  unsigned int u = __float_as_uint(f);
  u += 0x7FFFu + ((u >> 16) & 1u);   // round-to-nearest-even
  return (unsigned short)(u >> 16);
}

static __device__ __forceinline__ unsigned pack2bf(float lo, float hi) {
  return (unsigned)f2bf(lo) | ((unsigned)f2bf(hi) << 16);
}

static __device__ __forceinline__ float bf2f(unsigned short u) {
  return __uint_as_float((unsigned)u << 16);
}

static __device__ __forceinline__ float softplusf(float x) {
  return (x > 20.f) ? x : log1pf(__expf(x));
}

// ---------------------------------------------------------------------------
// Fused prep (single launch): bid<4096 -> q/k transpose+pos+bf16 (q scaled by
// SCALE*log2e); 4096..4607 -> v cast + colsum; 4608..4611 -> mask sums.
// ---------------------------------------------------------------------------
__global__ __launch_bounds__(256) void prep_all(
    const float* __restrict__ q, const float* __restrict__ k,
    const float* __restrict__ v,
    const float* __restrict__ me, const float* __restrict__ mm,
    const float* __restrict__ qp, const float* __restrict__ kp,
    unsigned short* __restrict__ qbf, unsigned short* __restrict__ kbf,
    unsigned short* __restrict__ vbf, float* __restrict__ colsum,
    float* __restrict__ msums) {
  int bid = blockIdx.x;
  int tid = threadIdx.x;

  if (bid < 4096) {
    // ---- q/k transpose [B,C,N] -> [B,N,C] (+pos), cast bf16
    int n0 = (bid & 127) * 32, c0 = ((bid >> 7) & 7) * 32;
    int z = bid >> 10;
    int b = z & 1, which = z >> 1;
    const float* src = which ? k : q;
    const float* pos = which ? kp : qp;
    unsigned short* dst = which ? kbf : qbf;
    float scl = which ? 1.0f : (SCALE * LOG2E);

    __shared__ float tile[32][33];
    int tx = tid & 31, ty = tid >> 5;
#pragma unroll
    for (int i = 0; i < 4; ++i) {
      int c = c0 + ty + i * 8;
      tile[ty + i * 8][tx] = src[((size_t)(b * DD + c)) * NN + n0 + tx];
    }
    __syncthreads();
#pragma unroll
    for (int i = 0; i < 4; ++i) {
      int n = n0 + ty + i * 8;
      float vv = (tile[tx][ty + i * 8] + pos[(size_t)n * DD + c0 + tx]) * scl;
      dst[((size_t)(b * NN + n)) * DD + c0 + tx] = f2bf(vv);
    }
  } else if (bid < 4608) {
    // ---- v cast (keeps [B,C,N] layout == V^T) + column sum
    int row = bid - 4096;  // b*256 + c
    const float* s = v + (size_t)row * NN;
    unsigned short* d = vbf + (size_t)row * NN;
    float sum = 0.f;
#pragma unroll
    for (int i = 0; i < 16; ++i) {
      int n = tid + i * 256;
      float vv = s[n];
      sum += vv;
      d[n] = f2bf(vv);
    }
#pragma unroll
    for (int off = 1; off < 64; off <<= 1) sum += __shfl_xor(sum, off);
    __shared__ float ps[4];
    if ((tid & 63) == 0) ps[tid >> 6] = sum;
    __syncthreads();
    if (tid == 0) colsum[row] = ps[0] + ps[1] + ps[2] + ps[3];
  } else {
    // ---- mask_map scalars (sum of squares of nearest-resized mask)
    int mb = bid - 4608;
    int b = mb >> 1, which = mb & 1;
    const float* m = which ? mm : me;
    float sum = 0.f;
#pragma unroll
    for (int i = 0; i < 16; ++i) {
      int p = tid + i * 256;
      int y = p >> 6, x = p & 63;
      float vv = m[(size_t)(b * 128 + 2 * y) * 128 + 2 * x];
      sum += vv * vv;
    }
#pragma unroll
    for (int off = 1; off < 64; off <<= 1) sum += __shfl_xor(sum, off);
    __shared__ float ps[4];
    if ((tid & 63) == 0) ps[tid >> 6] = sum;
    __syncthreads();
    if (tid == 0) msums[mb] = ps[0] + ps[1] + ps[2] + ps[3];
  }
}

// ---------------------------------------------------------------------------
// Register-staged K/V tiles (proven r11 mappings, unchanged).
// K: global row kv stored at LDS row rho = bitswap(kv bits 2<->3), XOR swz
//    -> QK^T output registers land exactly in PV A-fragment order.
// V: [256 d][32 kv], chunks ^= (d>>1)&3.
// ---------------------------------------------------------------------------
static __device__ __forceinline__ void load_k(
    const unsigned short* __restrict__ kb, int kvb, int wid, int lane, i32x4* kr) {
  int krow = wid * 8 + (lane >> 3);
  int kc = lane & 7;
  const unsigned short* kp = kb + (size_t)(kvb + krow) * DD;
#pragma unroll
  for (int i = 0; i < 4; ++i)
    kr[i] = *(const i32x4*)(kp + ((kc | (i << 3)) << 3));
}

static __device__ __forceinline__ void load_v(
    const unsigned short* __restrict__ vb, int kvb, int wid, int lane, i32x4* vr) {
  int vd = wid * 64 + lane;
  const unsigned short* vp = vb + (size_t)vd * NN + kvb;
#pragma unroll
  for (int i = 0; i < 4; ++i)
    vr[i] = *(const i32x4*)(vp + (i << 3));
}

static __device__ __forceinline__ void write_k(
    char* kdst, int wid, int lane, const i32x4* kr) {
  int krow = wid * 8 + (lane >> 3);
  int kc = lane & 7;
  int prow = ((krow & 4) << 2) | ((krow >> 3) << 2) | (krow & 3);  // kv->rho
  int rx = prow & 7;
#pragma unroll
  for (int i = 0; i < 4; ++i)
    *(i32x4*)(kdst + prow * 512 + (((kc | (i << 3)) ^ rx) << 4)) = kr[i];
}

static __device__ __forceinline__ void write_v(
    char* vdst, int wid, int lane, const i32x4* vr) {
  int vd = wid * 64 + lane;
  int vx = (vd >> 1) & 3;
#pragma unroll
  for (int i = 0; i < 4; ++i)
    *(i32x4*)(vdst + vd * 64 + ((i ^ vx) << 4)) = vr[i];
}

// QK^T MFMA cluster over the permuted K tile. Lane (ll,lg) output:
// st[t][r] = S[kv = lg*8 + 4t + r][q = ll]   (via the rho bit-swap)
static __device__ __forceinline__ void compute_qk(
    const unsigned short* __restrict__ Kc, const bf16x8* qB, int ll, int lg,
    f32x4* st) {
  st[0] = (f32x4){0.f, 0.f, 0.f, 0.f};
  st[1] = (f32x4){0.f, 0.f, 0.f, 0.f};
  __builtin_amdgcn_s_setprio(1);
#pragma unroll
  for (int t = 0; t < 2; ++t) {
    int row = t * 16 + ll;
    int rx = row & 7;
    const unsigned short* krd = Kc + row * 256;
#pragma unroll
    for (int kd = 0; kd < 8; ++kd) {
      bf16x8 kf = *(const bf16x8*)(krd + ((((kd << 2) | lg) ^ rx) << 3));
      st[t] = MFMA16(kf, qB[kd], st[t]);
    }
  }
  __builtin_amdgcn_s_setprio(0);
}

// ---------------------------------------------------------------------------
// Flash attention partial (round-13 structure, best known): swapped-QK^T,
// in-register log2-domain softmax with defer-max/defer-sum, pipelined
// QK(t+1)||softmax(t), shuffle-free P->PV via K-row permutation.
// K dbuf + V tribuf (80KB), ONE barrier/iter. QBLK=16/wave, 4 waves/block.
// ks=4: grid 512 = exactly 2 blocks/CU.
// ---------------------------------------------------------------------------
__global__ __launch_bounds__(256, 2) void attn_partial(
    const unsigned short* __restrict__ qbf,
    const unsigned short* __restrict__ kbf,
    const unsigned short* __restrict__ vbf,
    unsigned short* __restrict__ opartb, float* __restrict__ mlpart, int ks) {
  // XCD-chunked swizzle: consecutive bid chunk per XCD -> shared KV slice.
  int hwb = blockIdx.x;
  int bid = (hwb & 7) * ((int)gridDim.x >> 3) + (hwb >> 3);
  int qblk = bid & 63;           // 64-q block within (b,s)
  int combo = bid >> 6;          // (b, s)
  int b = combo / ks, sidx = combo % ks;
  int kvlen = NN / ks;
  int kv0 = sidx * kvlen;
  int nt = kvlen >> 5;

  int tid = threadIdx.x, wid = tid >> 6, lane = tid & 63;
  int ll = lane & 15, lg = lane >> 4;
  int qt16 = qblk * 4 + wid;     // this wave's 16-row q tile (0..255)

  __shared__ __align__(16) unsigned short Klds[2][32 * 256];
  __shared__ __align__(16) unsigned short Vlds[3][256 * 32];

  const unsigned short* kb = kbf + (size_t)b * NN * DD;
  const unsigned short* vb = vbf + (size_t)b * DD * NN;

  // Q B-fragments: col=ll -> q = ll, k = kd*32 + lg*8 + j  (SCALE*log2e folded)
  bf16x8 qB[8];
  {
    const unsigned short* qp0 = qbf + ((size_t)b * NN + (size_t)qt16 * 16) * DD;
#pragma unroll
    for (int kd = 0; kd < 8; ++kd)
      qB[kd] = *(const bf16x8*)(qp0 + (size_t)ll * DD + kd * 32 + lg * 8);
  }

  f32x4 o[16];
#pragma unroll
  for (int db = 0; db < 16; ++db) o[db] = (f32x4){0.f, 0.f, 0.f, 0.f};
  float m_ref = -1e30f;          // log2-domain reference max
  float sum_lane = 0.f;

  i32x4 kr[4], vr[4];
  // ---- prologue: stage tiles 0 and 1; QK(0); barrier protects K[0] reuse
  load_k(kb, kv0, wid, lane, kr);
  load_v(vb, kv0, wid, lane, vr);
  write_k((char*)&Klds[0][0], wid, lane, kr);
  write_v((char*)&Vlds[0][0], wid, lane, vr);
  if (nt > 1) {
    load_k(kb, kv0 + 32, wid, lane, kr);
    load_v(vb, kv0 + 32, wid, lane, vr);
    write_k((char*)&Klds[1][0], wid, lane, kr);
    write_v((char*)&Vlds[1][0], wid, lane, vr);
  }
  __syncthreads();

  f32x4 st[2];
  compute_qk(&Klds[0][0], qB, ll, lg, st);
  __syncthreads();   // all waves done reading K[0] before iter-0 overwrites it

  int vp = 0;        // V read slot (tt%3)
  int wp = 2;        // V write slot ((tt+2)%3)

  for (int tt = 0; tt < nt; ++tt) {
    bool have1 = (tt + 1 < nt);
    bool have2 = (tt + 2 < nt);
    if (have2) {
      load_k(kb, kv0 + (tt + 2) * 32, wid, lane, kr);
      load_v(vb, kv0 + (tt + 2) * 32, wid, lane, vr);
    }

    // ---- defer-max check on st (log2 domain)
    float tm = fmaxf(fmaxf(fmaxf(st[0][0], st[0][1]), fmaxf(st[0][2], st[0][3])),
                     fmaxf(fmaxf(st[1][0], st[1][1]), fmaxf(st[1][2], st[1][3])));
    if (__any(tm > m_ref + THR2)) {
      float tq = fmaxf(tm, __shfl_xor(tm, 16));
      tq = fmaxf(tq, __shfl_xor(tq, 32));
      float mn = fmaxf(m_ref, tq);
      float sc = EXP2(m_ref - mn);
      sum_lane *= sc;
      m_ref = mn;
#pragma unroll
      for (int r = 0; r < 4; ++r) {
        float sv = __shfl(sc, (lg << 2) + r);
#pragma unroll
        for (int db = 0; db < 16; ++db) o[db][r] *= sv;
      }
    }

    // ---- QK(t+1): MFMA pipe works while VALU does softmax(t) below
    f32x4 stn[2];
    if (have1) compute_qk(&Klds[(tt + 1) & 1][0], qB, ll, lg, stn);

    // ---- P = 2^(S - m_ref), bf16-packed; per-lane partial sums only.
    // K-row permutation makes pk the PV A-fragment directly: kv = lg*8+{0..7}
    unsigned pk[2][2];
#pragma unroll
    for (int t = 0; t < 2; ++t) {
      float a0 = EXP2(st[t][0] - m_ref);
      float a1 = EXP2(st[t][1] - m_ref);
      float a2 = EXP2(st[t][2] - m_ref);
      float a3 = EXP2(st[t][3] - m_ref);
      sum_lane += (a0 + a1) + (a2 + a3);
      pk[t][0] = pack2bf(a0, a1);
      pk[t][1] = pack2bf(a2, a3);
    }
    i32x4 fi = (i32x4){(int)pk[0][0], (int)pk[0][1], (int)pk[1][0], (int)pk[1][1]};
    bf16x8 pa = __builtin_bit_cast(bf16x8, fi);

    // ---- O += P V  (B-frag: col=ll -> d = db*16+ll, k = kv) from V[vp]
    const unsigned short* Vc = &Vlds[vp][0];
    __builtin_amdgcn_s_setprio(1);
#pragma unroll
    for (int db = 0; db < 16; ++db) {
      int d = (db << 4) + ll;
      bf16x8 vf = *(const bf16x8*)(Vc + d * 32 + ((lg ^ ((d >> 1) & 3)) << 3));
      o[db] = MFMA16(pa, vf, o[db]);
    }
    __builtin_amdgcn_s_setprio(0);

    // ---- stage t+2: K into K[tt&1] (free), V into V[wp] (free)
    if (have2) {
      write_k((char*)&Klds[tt & 1][0], wid, lane, kr);
      write_v((char*)&Vlds[wp][0], wid, lane, vr);
    }
    __syncthreads();

    if (have1) { st[0] = stn[0]; st[1] = stn[1]; }
    vp = (vp == 2) ? 0 : vp + 1;
    wp = (wp == 2) ? 0 : wp + 1;
  }

  // ---- final row-sum reduce (once per kernel)
  sum_lane += __shfl_xor(sum_lane, 16);
  sum_lane += __shfl_xor(sum_lane, 32);

  // ---- epilogue: bf16 unnormalized O (layout [d][q] per slot) + (m,l)
  size_t slot = (size_t)(b * 256 + qt16) * ks + sidx;
  unsigned short* op = opartb + slot * 4096;
#pragma unroll
  for (int db = 0; db < 16; ++db) {
    unsigned u0 = pack2bf(o[db][0], o[db][1]);
    unsigned u1 = pack2bf(o[db][2], o[db][3]);
    unsigned* p = (unsigned*)&op[(size_t)((db * 16 + ll) * 16 + lg * 4)];
    p[0] = u0;
    p[1] = u1;
  }
  if (lg == 0) {
    float* mlp = mlpart + slot * 32;
    mlp[ll * 2 + 0] = m_ref;     // log2-domain max
    mlp[ll * 2 + 1] = sum_lane;
  }
}

// ---------------------------------------------------------------------------
// Combine: merge ks bf16 partials (m in log2 domain -> exp2 weights),
// normalize, add softplus-bias * colsum. grid 512 = (b, qt16); thread = d.
// ---------------------------------------------------------------------------
__global__ __launch_bounds__(256) void attn_combine(
    const unsigned short* __restrict__ opartb, const float* __restrict__ mlpart,
    const float* __restrict__ colsum, const float* __restrict__ msums,
    const float* __restrict__ bias_eye, const float* __restrict__ bias_mouth,
    float* __restrict__ out, int ks) {
  int gb = blockIdx.x;
  int b = gb >> 8, qt16 = gb & 255;
  int tid = threadIdx.x;
  __shared__ float wtab[8][16];
  size_t slot0 = (size_t)(b * 256 + qt16) * ks;

  if (tid < 16) {
    int q = tid;
    float m[8], l[8], w[8];
    float M = -1e30f;
#pragma unroll
    for (int s = 0; s < 8; ++s) {
      if (s < ks) {
        m[s] = mlpart[(slot0 + s) * 32 + q * 2 + 0];
        l[s] = mlpart[(slot0 + s) * 32 + q * 2 + 1];
        M = fmaxf(M, m[s]);
      } else { m[s] = -1e30f; l[s] = 0.f; }
    }
    float L = 0.f;
#pragma unroll
    for (int s = 0; s < 8; ++s) {
      w[s] = (s < ks) ? EXP2(m[s] - M) : 0.f;
      L += l[s] * w[s];
    }
    float invL = 1.f / L;
#pragma unroll
    for (int s = 0; s < 8; ++s) wtab[s][q] = w[s] * invL;
  }
  __syncthreads();

  int d = tid;
  float sb = softplusf(bias_eye[0] * msums[b * 2 + 0]) +
             softplusf(bias_mouth[0] * msums[b * 2 + 1]);
  float cs = colsum[b * DD + d] * sb;

  float acc[16];
#pragma unroll
  for (int q = 0; q < 16; ++q) acc[q] = cs;

#pragma unroll
  for (int s = 0; s < 8; ++s) {
    if (s < ks) {
      const unsigned short* op = opartb + (slot0 + s) * 4096 + d * 16;
#pragma unroll
      for (int q = 0; q < 16; ++q)
        acc[q] += wtab[s][q] * bf2f(op[q]);
    }
  }

  float* ob = out + ((size_t)(b * DD + d)) * NN + qt16 * 16;
#pragma unroll
  for (int g = 0; g < 4; ++g) {
    f32x4 v = (f32x4){acc[g * 4 + 0], acc[g * 4 + 1], acc[g * 4 + 2], acc[g * 4 + 3]};
    *(f32x4*)&ob[g * 4] = v;
  }
}

// ---------------------------------------------------------------------------
extern "C" void kernel_launch(void* const* d_in, const int* in_sizes, int n_in,
                              void* d_out, int out_size, void* d_ws, size_t ws_size,
                              hipStream_t stream) {
  (void)in_sizes; (void)n_in; (void)out_size;
  const float* queries    = (const float*)d_in[0];
  const float* keys       = (const float*)d_in[1];
  const float* values     = (const float*)d_in[2];
  const float* mask_eye   = (const float*)d_in[3];
  const float* mask_mouth = (const float*)d_in[4];
  const float* q_pos      = (const float*)d_in[5];
  const float* k_pos      = (const float*)d_in[6];
  const float* bias_eye   = (const float*)d_in[7];
  const float* bias_mouth = (const float*)d_in[8];
  float* out = (float*)d_out;

  char* w = (char*)d_ws;
  unsigned short* qbf = (unsigned short*)(w);                     // 4 MB
  unsigned short* kbf = (unsigned short*)(w + ((size_t)4 << 20)); // 4 MB
  unsigned short* vbf = (unsigned short*)(w + ((size_t)8 << 20)); // 4 MB
  float* colsum = (float*)(w + ((size_t)12 << 20));               // 1 KB
  float* msums  = (float*)(w + ((size_t)12 << 20) + 4096);        // 16 B

  const size_t opart_off = ((size_t)12 << 20) + 8192;
  const size_t opart_chunk = (size_t)512 * 8192;  // per split: 512 slots*8KB bf16
  const size_t ml_chunk = (size_t)512 * 128;      // per split: 512 slots*128B

  // ks=4: grid 512 = exactly 2 blocks/CU (the LDS-capped residency).
  int ks = 1;
  for (int cand = 4; cand >= 1; cand >>= 1) {
    if (ws_size >= opart_off + (size_t)cand * (opart_chunk + ml_chunk)) { ks = cand; break; }
  }

  unsigned short* opartp = (unsigned short*)(w + opart_off);
  float* mlp = (float*)(w + opart_off + (size_t)ks * opart_chunk);

  prep_all<<<4612, 256, 0, stream>>>(queries, keys, values, mask_eye, mask_mouth,
                                     q_pos, k_pos, qbf, kbf, vbf, colsum, msums);

  attn_partial<<<128 * ks, 256, 0, stream>>>(qbf, kbf, vbf, opartp, mlp, ks);
  attn_combine<<<512, 256, 0, stream>>>(opartp, mlp, colsum, msums,
                                        bias_eye, bias_mouth, out, ks);
}